// Round 1
// baseline (214.361 us; speedup 1.0000x reference)
//
#include <hip/hip_runtime.h>
#include <hip/hip_bf16.h>
#include <stdint.h>

// Problem constants
#define Bq 8
#define Lq 2048
#define Dq 1024
#define Pq 4
#define Kq 4096          // D*P
#define LPAD 2056        // 3 zero rows + 2048 data + 5 slack, per batch
// GEMM tiling (m97 structure)
#define BM 128
#define BN 128
#define BKq 64

typedef __attribute__((ext_vector_type(8))) short short8;   // 8 bf16 (4 VGPRs)
typedef __attribute__((ext_vector_type(4))) float f32x4;

__device__ __forceinline__ unsigned short f2bf(float f) {
  unsigned u = __float_as_uint(f);
  u += 0x7FFFu + ((u >> 16) & 1u);   // round-to-nearest-even
  return (unsigned short)(u >> 16);
}

__device__ __forceinline__ void gload_lds16(const void* g, void* l) {
  __builtin_amdgcn_global_load_lds(
      (const __attribute__((address_space(1))) void*)g,
      (__attribute__((address_space(3))) void*)l, 16, 0, 0);
}

// ---- prep 1: Wp[d][i*1024 + d'] = bf16(W[d][d'*4 + i]) ----
// one thread per 8 consecutive source floats (= d',d'+1 x i=0..3)
__global__ void k_prep_w(const float* __restrict__ W, unsigned short* __restrict__ Wp) {
  unsigned g = blockIdx.x * blockDim.x + threadIdx.x;   // 524288 threads
  unsigned base = g * 8;
  unsigned d = base >> 12;
  unsigned rem = base & 4095;
  unsigned dp = rem >> 2;                               // even
  const float4* src = (const float4*)(W + base);
  float4 v0 = src[0];
  float4 v1 = src[1];
  float a0[4] = {v0.x, v0.y, v0.z, v0.w};
  float a1[4] = {v1.x, v1.y, v1.z, v1.w};
#pragma unroll
  for (int i = 0; i < 4; ++i) {
    unsigned packed = (unsigned)f2bf(a0[i]) | ((unsigned)f2bf(a1[i]) << 16);
    *(unsigned*)(Wp + (size_t)d * 4096 + (size_t)i * 1024 + dp) = packed;
  }
}

// ---- prep 2: xp[b][r][d] = (3 <= r < 2051) ? bf16(x[b][r-3][d]) : 0 ----
__global__ void k_prep_x(const float* __restrict__ x, unsigned short* __restrict__ xp) {
  unsigned g = blockIdx.x * blockDim.x + threadIdx.x;   // 2,105,344 threads
  unsigned base = g * 8;
  const unsigned total = (unsigned)Bq * LPAD * Dq;
  if (base >= total) return;
  unsigned t = base >> 10;            // b*LPAD + r
  unsigned b = t / LPAD;
  unsigned r = t - b * LPAD;
  unsigned d = base & 1023;
  short8 o;
  if (r >= 3 && r < 3 + Lq) {
    const float* s = x + ((size_t)b * Lq + (r - 3)) * Dq + d;
    float4 v0 = *(const float4*)(s);
    float4 v1 = *(const float4*)(s + 4);
    o[0] = (short)f2bf(v0.x); o[1] = (short)f2bf(v0.y);
    o[2] = (short)f2bf(v0.z); o[3] = (short)f2bf(v0.w);
    o[4] = (short)f2bf(v1.x); o[5] = (short)f2bf(v1.y);
    o[6] = (short)f2bf(v1.z); o[7] = (short)f2bf(v1.w);
  } else {
    o = (short8)0;
  }
  *(short8*)(xp + base) = o;
}

// ---- main GEMM: C[m][n] = sum_k A[m][k]*Wp[n][k] + bias[n] ----
// A[m][i*1024+d'] = xp[b][l+3-i][d'], m = b*2048 + l
__global__ void __launch_bounds__(256)
k_gemm(const unsigned short* __restrict__ xp,
       const unsigned short* __restrict__ Wp,
       const float* __restrict__ bias,
       float* __restrict__ out) {
  __shared__ __attribute__((aligned(16))) short smemA[BM * BKq];  // 16 KiB
  __shared__ __attribute__((aligned(16))) short smemB[BN * BKq];  // 16 KiB

  const int tid = threadIdx.x;
  const int lane = tid & 63;
  const int w = tid >> 6;             // wave 0..3
  const int wr = w >> 1, wc = w & 1;  // 2x2 wave grid, each wave 64x64 out

  const int n0 = blockIdx.x * BN;     // 0..7  * 128
  const int m0 = blockIdx.y * BM;     // 0..127 * 128
  const int b  = m0 >> 11;
  const int l0 = m0 & 2047;

  f32x4 acc[4][4] = {};

  const int srow = tid >> 3;          // 0..31 (per-issue row within 32-row chunk)
  const int scol = (tid & 7) * 8;     // 0..56

  for (int kt = 0; kt < Kq / BKq; ++kt) {
    const int i  = kt >> 4;                    // phrase offset 0..3
    const int d0 = (kt & 15) << 6;             // d' base
    const size_t aOff = ((size_t)(b * LPAD + l0 + 3 - i)) * Dq + d0;
    const size_t bOff = (size_t)n0 * Kq + (size_t)kt * BKq;

    // stage A,B tiles: 4 issues x 256 threads x 16B each per tile
#pragma unroll
    for (int q = 0; q < 4; ++q) {
      const int r = q * 32 + srow;
      gload_lds16(xp + aOff + (size_t)r * Dq + scol, &smemA[(q * 256 + w * 64) * 8]);
      gload_lds16(Wp + bOff + (size_t)r * Kq + scol, &smemB[(q * 256 + w * 64) * 8]);
    }
    __syncthreads();   // drains vmcnt(0) then barrier

#pragma unroll
    for (int kk = 0; kk < 2; ++kk) {
      short8 af[4], bf[4];
      const int ko = kk * 32 + (lane >> 4) * 8;
#pragma unroll
      for (int mi = 0; mi < 4; ++mi)
        af[mi] = *(const short8*)&smemA[(wr * 64 + mi * 16 + (lane & 15)) * BKq + ko];
#pragma unroll
      for (int ni = 0; ni < 4; ++ni)
        bf[ni] = *(const short8*)&smemB[(wc * 64 + ni * 16 + (lane & 15)) * BKq + ko];
#pragma unroll
      for (int mi = 0; mi < 4; ++mi)
#pragma unroll
        for (int ni = 0; ni < 4; ++ni)
          acc[mi][ni] = __builtin_amdgcn_mfma_f32_16x16x32_bf16(af[mi], bf[ni], acc[mi][ni], 0, 0, 0);
    }
    __syncthreads();
  }

  // epilogue: C/D layout col = lane&15, row = (lane>>4)*4 + reg
#pragma unroll
  for (int ni = 0; ni < 4; ++ni) {
    const int col = n0 + wc * 64 + ni * 16 + (lane & 15);
    const float bv = bias[col];
#pragma unroll
    for (int mi = 0; mi < 4; ++mi) {
      const int row0 = m0 + wr * 64 + mi * 16 + ((lane >> 4) << 2);
#pragma unroll
      for (int t2 = 0; t2 < 4; ++t2)
        out[(size_t)(row0 + t2) * Dq + col] = acc[mi][ni][t2] + bv;
    }
  }
}

// ---- slow-but-correct fallback if workspace is too small ----
__global__ void k_naive(const float* __restrict__ x, const float* __restrict__ W,
                        const float* __restrict__ bias, float* __restrict__ out) {
  size_t g = (size_t)blockIdx.x * blockDim.x + threadIdx.x;
  const size_t total = (size_t)Bq * Lq * Dq;
  if (g >= total) return;
  int d = (int)(g & 1023);
  int l = (int)((g >> 10) & 2047);
  int b = (int)(g >> 21);
  float s = bias[d];
  for (int i = 0; i < Pq; ++i) {
    if (l - i < 0) continue;
    const float* xr = x + ((size_t)b * Lq + (l - i)) * Dq;
    const float* wr = W + (size_t)d * Kq + i;
    float accv = 0.f;
    for (int dp = 0; dp < Dq; ++dp) accv += xr[dp] * wr[(size_t)dp * 4];
    s += accv;
  }
  out[g] = s;
}

extern "C" void kernel_launch(void* const* d_in, const int* in_sizes, int n_in,
                              void* d_out, int out_size, void* d_ws, size_t ws_size,
                              hipStream_t stream) {
  const float* x    = (const float*)d_in[0];
  const float* W    = (const float*)d_in[1];
  const float* bias = (const float*)d_in[2];
  float* out = (float*)d_out;

  const size_t WP_BYTES = (size_t)Dq * Kq * sizeof(unsigned short);        // 8 MiB
  const size_t XP_BYTES = (size_t)Bq * LPAD * Dq * sizeof(unsigned short); // ~33.7 MB

  if (ws_size < WP_BYTES + XP_BYTES) {
    const size_t total = (size_t)Bq * Lq * Dq;
    k_naive<<<(unsigned)((total + 255) / 256), 256, 0, stream>>>(x, W, bias, out);
    return;
  }

  unsigned short* Wp = (unsigned short*)d_ws;
  unsigned short* xp = (unsigned short*)((char*)d_ws + WP_BYTES);

  k_prep_w<<<2048, 256, 0, stream>>>(W, Wp);      // 4M floats / 8 per thread
  k_prep_x<<<8224, 256, 0, stream>>>(x, xp);      // 16.84M elems / 8 per thread
  k_gemm<<<dim3(Dq / BN, (Bq * Lq) / BM), 256, 0, stream>>>(xp, Wp, bias, out);
}

// Round 2
// 137.391 us; speedup vs baseline: 1.5602x; 1.5602x over previous
//
#include <hip/hip_runtime.h>
#include <hip/hip_bf16.h>
#include <stdint.h>

// Problem constants
#define Bq 8
#define Lq 2048
#define Dq 1024
#define Pq 4
#define Kq 4096          // D*P
#define LPAD 2056        // 3 zero rows + 2048 data + 5 slack, per batch
// GEMM tiling: 256x256 8-phase template (m201 structure)
#define BM 256
#define BN 256
#define BK 64

typedef __attribute__((ext_vector_type(8))) short short8;   // 8 bf16 (4 VGPRs)
typedef __attribute__((ext_vector_type(4))) float f32x4;

__device__ __forceinline__ unsigned short f2bf(float f) {
  unsigned u = __float_as_uint(f);
  u += 0x7FFFu + ((u >> 16) & 1u);   // round-to-nearest-even
  return (unsigned short)(u >> 16);
}

__device__ __forceinline__ void gload_lds16(const void* g, void* l) {
  __builtin_amdgcn_global_load_lds(
      (const __attribute__((address_space(1))) void*)g,
      (__attribute__((address_space(3))) void*)l, 16, 0, 0);
}

// ---- prep 1: Wp[d][i*1024 + d'] = bf16(W[d][d'*4 + i]) ----
__global__ void k_prep_w(const float* __restrict__ W, unsigned short* __restrict__ Wp) {
  unsigned g = blockIdx.x * blockDim.x + threadIdx.x;   // 524288 threads
  unsigned base = g * 8;
  unsigned d = base >> 12;
  unsigned rem = base & 4095;
  unsigned dp = rem >> 2;                               // even
  const float4* src = (const float4*)(W + base);
  float4 v0 = src[0];
  float4 v1 = src[1];
  float a0[4] = {v0.x, v0.y, v0.z, v0.w};
  float a1[4] = {v1.x, v1.y, v1.z, v1.w};
#pragma unroll
  for (int i = 0; i < 4; ++i) {
    unsigned packed = (unsigned)f2bf(a0[i]) | ((unsigned)f2bf(a1[i]) << 16);
    *(unsigned*)(Wp + (size_t)d * 4096 + (size_t)i * 1024 + dp) = packed;
  }
}

// ---- prep 2: xp[b][r][d] = (3 <= r < 2051) ? bf16(x[b][r-3][d]) : 0 ----
__global__ void k_prep_x(const float* __restrict__ x, unsigned short* __restrict__ xp) {
  unsigned g = blockIdx.x * blockDim.x + threadIdx.x;
  unsigned base = g * 8;
  const unsigned total = (unsigned)Bq * LPAD * Dq;
  if (base >= total) return;
  unsigned t = base >> 10;            // b*LPAD + r
  unsigned b = t / LPAD;
  unsigned r = t - b * LPAD;
  unsigned d = base & 1023;
  short8 o;
  if (r >= 3 && r < 3 + Lq) {
    const float* s = x + ((size_t)b * Lq + (r - 3)) * Dq + d;
    float4 v0 = *(const float4*)(s);
    float4 v1 = *(const float4*)(s + 4);
    o[0] = (short)f2bf(v0.x); o[1] = (short)f2bf(v0.y);
    o[2] = (short)f2bf(v0.z); o[3] = (short)f2bf(v0.w);
    o[4] = (short)f2bf(v1.x); o[5] = (short)f2bf(v1.y);
    o[6] = (short)f2bf(v1.z); o[7] = (short)f2bf(v1.w);
  } else {
    o = (short8)0;
  }
  *(short8*)(xp + base) = o;
}

// ================= 256x256 8-phase GEMM =================
// C[m][n] = sum_k A[m][k]*Wp[n][k] + bias[n],  A[m][i*1024+d'] = xp[b][l+3-i][d']
//
// LDS (128 KiB): per dbuf(2): [Ah0 16K][Ah1 16K][Bh0 16K][Bh1 16K]
//   A-half h region row r (0..127): global A row m0 + (r>>6)*128 + h*64 + (r&63)
//   B-half h region row r (0..127): global B row n0 + (r>>5)*64 + h*32 + (r&31)
//   byte within row (128B): SWIZZLED  phys_c = log_c ^ ((r&7)<<4)
// 8 waves: wm = w>>2 (rows wm*128+..), wn = w&3 (cols wn*64+..)
// Phase quadrants per K-tile: (mh,nh) = (0,0),(0,1),(1,1),(1,0)

#define VM6 asm volatile("s_waitcnt vmcnt(6)" ::: "memory")
#define VM4 asm volatile("s_waitcnt vmcnt(4)" ::: "memory")
#define VM0 asm volatile("s_waitcnt vmcnt(0)" ::: "memory")
#define NOPS ((void)0)

#define STAGE_A(buf, kt, h) do { \
    const int i_ = (kt) >> 4; const int d0_ = ((kt) & 15) << 6; \
    _Pragma("unroll") for (int q_ = 0; q_ < 2; ++q_) { \
      const unsigned short* src_ = xp + (((size_t)(aRowBase + q_ * 128 + (h) * 64 - i_)) << 10) + d0_ + clog; \
      gload_lds16(src_, lds + ((buf) << 16) + ((h) << 14) + (q_ << 13) + (tid << 4)); \
    } } while (0)

#define STAGE_B(buf, kt, h) do { \
    _Pragma("unroll") for (int q_ = 0; q_ < 2; ++q_) { \
      const unsigned short* src_ = Wp + (((size_t)(nBase0 + q_ * 128 + (h) * 32)) << 12) + ((kt) << 6) + clog; \
      gload_lds16(src_, lds + ((buf) << 16) + 32768 + ((h) << 14) + (q_ << 13) + (tid << 4)); \
    } } while (0)

#define PHASE(buf, mh, nh, LOADA, LOADB, STAGE_STMT, VM_STMT) do { \
    if (LOADA) { \
      _Pragma("unroll") for (int mi = 0; mi < 4; ++mi) \
      _Pragma("unroll") for (int kk = 0; kk < 2; ++kk) \
        fa[mi][kk] = *(const short8*)(lds + ((buf) << 16) + ((mh) << 14) + aRowByte[mi] + colByte[kk]); \
    } \
    if (LOADB) { \
      _Pragma("unroll") for (int ni = 0; ni < 2; ++ni) \
      _Pragma("unroll") for (int kk = 0; kk < 2; ++kk) \
        fb[ni][kk] = *(const short8*)(lds + ((buf) << 16) + 32768 + ((nh) << 14) + bRowByte[ni] + colByte[kk]); \
    } \
    STAGE_STMT; \
    VM_STMT; \
    __builtin_amdgcn_s_barrier(); \
    __builtin_amdgcn_sched_barrier(0); \
    __builtin_amdgcn_s_setprio(1); \
    _Pragma("unroll") for (int mi = 0; mi < 4; ++mi) \
    _Pragma("unroll") for (int ni = 0; ni < 2; ++ni) \
    _Pragma("unroll") for (int kk = 0; kk < 2; ++kk) \
      acc[(mh) * 4 + mi][(nh) * 2 + ni] = __builtin_amdgcn_mfma_f32_16x16x32_bf16( \
          fa[mi][kk], fb[ni][kk], acc[(mh) * 4 + mi][(nh) * 2 + ni], 0, 0, 0); \
    __builtin_amdgcn_s_setprio(0); \
    __builtin_amdgcn_s_barrier(); \
    __builtin_amdgcn_sched_barrier(0); \
  } while (0)

__global__ void __launch_bounds__(512, 2)
k_gemm(const unsigned short* __restrict__ xp,
       const unsigned short* __restrict__ Wp,
       const float* __restrict__ bias,
       float* __restrict__ out) {
  __shared__ __attribute__((aligned(16))) unsigned char lds[131072];

  const int tid  = threadIdx.x;
  const int lane = tid & 63;
  const int w    = tid >> 6;       // 0..7
  const int wm   = w >> 2;         // 0..1
  const int wn   = w & 3;          // 0..3

  // bijective XCD swizzle (256 blocks, 256 % 8 == 0): each XCD gets a
  // contiguous 8-mtile x 4-ntile chunk -> A fetched once per XCD.
  const int bid = blockIdx.x;
  const int swz = (bid & 7) * 32 + (bid >> 3);
  const int m0 = (swz >> 2) * BM;
  const int n0 = (swz & 3) * BN;
  const int b  = m0 >> 11;
  const int l0 = m0 & 2047;

  // ---- staging geometry (per thread) ----
  const int sr0 = tid >> 3;                                  // region row, issue q adds q*64
  const int clog = ((tid & 7) ^ (sr0 & 7)) << 3;             // pre-swizzled source elem offset
  const int aRowBase = b * LPAD + l0 + 3 + sr0;
  const int nBase0 = n0 + ((sr0 >> 5) << 6) + (sr0 & 31);

  // ---- ds_read geometry (per thread) ----
  int aRowByte[4], bRowByte[2], colByte[2];
#pragma unroll
  for (int mi = 0; mi < 4; ++mi) aRowByte[mi] = (wm * 64 + mi * 16 + (lane & 15)) << 7;
#pragma unroll
  for (int ni = 0; ni < 2; ++ni) bRowByte[ni] = (wn * 32 + ni * 16 + (lane & 15)) << 7;
#pragma unroll
  for (int kk = 0; kk < 2; ++kk)
    colByte[kk] = (kk * 64 + ((lane >> 4) << 4)) ^ ((lane & 7) << 4);

  f32x4 acc[8][4] = {};
  short8 fa[4][2], fb[2][2];

  // ---- prologue: tile0 (buf0) fully, tile1 (buf1) 3 halves ----
  STAGE_A(0, 0, 0);
  STAGE_B(0, 0, 1);
  STAGE_A(0, 0, 1);
  STAGE_B(0, 0, 0);
  VM4;
  STAGE_A(1, 1, 0);
  STAGE_B(1, 1, 1);
  STAGE_A(1, 1, 1);
  VM6;                               // tile0 fully landed (per-wave)
  __builtin_amdgcn_s_barrier();      // all waves' tile0 landed
  __builtin_amdgcn_sched_barrier(0);

  // ---- main loop: 31 iters, tiles 0..61 ----
#pragma unroll 1
  for (int it = 0; it < 31; ++it) {
    const int kt0 = it * 2;
    PHASE(0, 0, 0, 1, 1, STAGE_B(1, kt0 + 1, 0), NOPS);
    PHASE(0, 0, 1, 0, 1, STAGE_A(0, kt0 + 2, 0), NOPS);
    PHASE(0, 1, 1, 1, 0, STAGE_B(0, kt0 + 2, 1), NOPS);
    PHASE(0, 1, 0, 0, 1, STAGE_A(0, kt0 + 2, 1), VM6);   // tile kt0+1 landed
    PHASE(1, 0, 0, 1, 1, STAGE_B(0, kt0 + 2, 0), NOPS);
    PHASE(1, 0, 1, 0, 1, STAGE_A(1, kt0 + 3, 0), NOPS);
    PHASE(1, 1, 1, 1, 0, STAGE_B(1, kt0 + 3, 1), NOPS);
    PHASE(1, 1, 0, 0, 1, STAGE_A(1, kt0 + 3, 1), VM6);   // tile kt0+2 landed
  }

  // ---- epilogue: tiles 62 (buf0), 63 (buf1) ----
  PHASE(0, 0, 0, 1, 1, STAGE_B(1, 63, 0), NOPS);
  PHASE(0, 0, 1, 0, 1, NOPS, NOPS);
  PHASE(0, 1, 1, 1, 0, NOPS, NOPS);
  PHASE(0, 1, 0, 0, 1, NOPS, VM0);                        // tile 63 landed
  PHASE(1, 0, 0, 1, 1, NOPS, NOPS);
  PHASE(1, 0, 1, 0, 1, NOPS, NOPS);
  PHASE(1, 1, 1, 1, 0, NOPS, NOPS);
  PHASE(1, 1, 0, 0, 1, NOPS, NOPS);

  // ---- C write: col = lane&15, row = (lane>>4)*4 + reg ----
#pragma unroll
  for (int nig = 0; nig < 4; ++nig) {
    const int col = n0 + wn * 64 + nig * 16 + (lane & 15);
    const float bv = bias[col];
#pragma unroll
    for (int mig = 0; mig < 8; ++mig) {
      const int row0 = m0 + wm * 128 + mig * 16 + ((lane >> 4) << 2);
#pragma unroll
      for (int t2 = 0; t2 < 4; ++t2)
        out[(size_t)(row0 + t2) * Dq + col] = acc[mig][nig][t2] + bv;
    }
  }
}

// ---- slow-but-correct fallback if workspace is too small ----
__global__ void k_naive(const float* __restrict__ x, const float* __restrict__ W,
                        const float* __restrict__ bias, float* __restrict__ out) {
  size_t g = (size_t)blockIdx.x * blockDim.x + threadIdx.x;
  const size_t total = (size_t)Bq * Lq * Dq;
  if (g >= total) return;
  int d = (int)(g & 1023);
  int l = (int)((g >> 10) & 2047);
  int b = (int)(g >> 21);
  float s = bias[d];
  for (int i = 0; i < Pq; ++i) {
    if (l - i < 0) continue;
    const float* xr = x + ((size_t)b * Lq + (l - i)) * Dq;
    const float* wr = W + (size_t)d * Kq + i;
    float accv = 0.f;
    for (int dp = 0; dp < Dq; ++dp) accv += xr[dp] * wr[(size_t)dp * 4];
    s += accv;
  }
  out[g] = s;
}

extern "C" void kernel_launch(void* const* d_in, const int* in_sizes, int n_in,
                              void* d_out, int out_size, void* d_ws, size_t ws_size,
                              hipStream_t stream) {
  const float* x    = (const float*)d_in[0];
  const float* W    = (const float*)d_in[1];
  const float* bias = (const float*)d_in[2];
  float* out = (float*)d_out;

  const size_t WP_BYTES = (size_t)Dq * Kq * sizeof(unsigned short);        // 8 MiB
  const size_t XP_BYTES = (size_t)Bq * LPAD * Dq * sizeof(unsigned short); // ~33.7 MB

  if (ws_size < WP_BYTES + XP_BYTES) {
    const size_t total = (size_t)Bq * Lq * Dq;
    k_naive<<<(unsigned)((total + 255) / 256), 256, 0, stream>>>(x, W, bias, out);
    return;
  }

  unsigned short* Wp = (unsigned short*)d_ws;
  unsigned short* xp = (unsigned short*)((char*)d_ws + WP_BYTES);

  k_prep_w<<<2048, 256, 0, stream>>>(W, Wp);
  k_prep_x<<<8224, 256, 0, stream>>>(x, xp);
  k_gemm<<<dim3((Bq * Lq / BM) * (Dq / BN)), 512, 0, stream>>>(xp, Wp, bias, out);
}

// Round 3
// 135.626 us; speedup vs baseline: 1.5805x; 1.0130x over previous
//
#include <hip/hip_runtime.h>
#include <hip/hip_bf16.h>
#include <stdint.h>

// Problem constants
#define Bq 8
#define Lq 2048
#define Dq 1024
#define Pq 4
#define Kq 4096          // D*P
#define LPAD 2056        // 3 zero rows + 2048 data + 5 slack, per batch
// GEMM tiling: 256x256 8-phase template (m201 structure)
#define BM 256
#define BN 256
#define BK 64

typedef __attribute__((ext_vector_type(8))) short short8;   // 8 bf16 (4 VGPRs)
typedef __attribute__((ext_vector_type(4))) float f32x4;

__device__ __forceinline__ unsigned short f2bf(float f) {
  unsigned u = __float_as_uint(f);
  u += 0x7FFFu + ((u >> 16) & 1u);   // round-to-nearest-even
  return (unsigned short)(u >> 16);
}

__device__ __forceinline__ void gload_lds16(const void* g, void* l) {
  __builtin_amdgcn_global_load_lds(
      (const __attribute__((address_space(1))) void*)g,
      (__attribute__((address_space(3))) void*)l, 16, 0, 0);
}

// ---- merged prep: blocks [0,8224) do xp, blocks [8224,10272) do Wp ----
// xp[b][r][d] = (3 <= r < 2051) ? bf16(x[b][r-3][d]) : 0
// Wp[d][i*1024 + d'] = bf16(W[d][d'*4 + i])
__global__ void k_prep(const float* __restrict__ x, const float* __restrict__ W,
                       unsigned short* __restrict__ xp, unsigned short* __restrict__ Wp) {
  if (blockIdx.x < 8224u) {
    unsigned g = blockIdx.x * blockDim.x + threadIdx.x;
    unsigned base = g * 8;
    const unsigned total = (unsigned)Bq * LPAD * Dq;
    if (base >= total) return;
    unsigned t = base >> 10;            // b*LPAD + r
    unsigned b = t / LPAD;
    unsigned r = t - b * LPAD;
    unsigned d = base & 1023;
    short8 o;
    if (r >= 3 && r < 3 + Lq) {
      const float* s = x + ((size_t)b * Lq + (r - 3)) * Dq + d;
      float4 v0 = *(const float4*)(s);
      float4 v1 = *(const float4*)(s + 4);
      o[0] = (short)f2bf(v0.x); o[1] = (short)f2bf(v0.y);
      o[2] = (short)f2bf(v0.z); o[3] = (short)f2bf(v0.w);
      o[4] = (short)f2bf(v1.x); o[5] = (short)f2bf(v1.y);
      o[6] = (short)f2bf(v1.z); o[7] = (short)f2bf(v1.w);
    } else {
      o = (short8)0;
    }
    *(short8*)(xp + base) = o;
  } else {
    unsigned g = (blockIdx.x - 8224u) * blockDim.x + threadIdx.x;
    unsigned base = g * 8;
    unsigned d = base >> 12;
    unsigned rem = base & 4095;
    unsigned dp = rem >> 2;                               // even
    const float4* src = (const float4*)(W + base);
    float4 v0 = src[0];
    float4 v1 = src[1];
    float a0[4] = {v0.x, v0.y, v0.z, v0.w};
    float a1[4] = {v1.x, v1.y, v1.z, v1.w};
#pragma unroll
    for (int i = 0; i < 4; ++i) {
      unsigned packed = (unsigned)f2bf(a0[i]) | ((unsigned)f2bf(a1[i]) << 16);
      *(unsigned*)(Wp + (size_t)d * 4096 + (size_t)i * 1024 + dp) = packed;
    }
  }
}

// ================= 256x256 8-phase GEMM =================
// C[m][n] = sum_k A[m][k]*Wp[n][k] + bias[n],  A[m][i*1024+d'] = xp[b][l+3-i][d']
//
// LDS (128 KiB): per dbuf(2): [Ah0 16K][Ah1 16K][Bh0 16K][Bh1 16K]
//   A-half h region row r (0..127): global A row m0 + (r>>6)*128 + h*64 + (r&63)
//   B-half h region row r (0..127): global B row n0 + (r>>5)*64 + h*32 + (r&31)
//   byte within row (128B): SWIZZLED  phys_c = log_c ^ ((r&7)<<4)
// 8 waves: wm = w>>2 (rows wm*128+..), wn = w&3 (cols wn*64+..)
// Phase quadrants per K-tile: (mh,nh) = (0,0),(0,1),(1,1),(1,0)
//
// Sched discipline: barriers + counted vmcnt enforce the pipeline;
// sched_barrier(0x106) = VALU|SALU|DS_READ may cross (latency hiding),
// VMEM (gload issue order = vmcnt math!), DS_WRITE, MFMA may NOT.

#define VM6 asm volatile("s_waitcnt vmcnt(6)" ::: "memory")
#define VM4 asm volatile("s_waitcnt vmcnt(4)" ::: "memory")
#define VM0 asm volatile("s_waitcnt vmcnt(0)" ::: "memory")
#define NOPS ((void)0)
#define SCHED_RELAX __builtin_amdgcn_sched_barrier(0x106)

#define STAGE_A(buf, kt, h) do { \
    const int i_ = (kt) >> 4; const int d0_ = ((kt) & 15) << 6; \
    _Pragma("unroll") for (int q_ = 0; q_ < 2; ++q_) { \
      const unsigned short* src_ = xp + (((size_t)(aRowBase + q_ * 128 + (h) * 64 - i_)) << 10) + d0_ + clog; \
      gload_lds16(src_, lds + ((buf) << 16) + ((h) << 14) + (q_ << 13) + (tid << 4)); \
    } } while (0)

#define STAGE_B(buf, kt, h) do { \
    _Pragma("unroll") for (int q_ = 0; q_ < 2; ++q_) { \
      const unsigned short* src_ = Wp + (((size_t)(nBase0 + q_ * 128 + (h) * 32)) << 12) + ((kt) << 6) + clog; \
      gload_lds16(src_, lds + ((buf) << 16) + 32768 + ((h) << 14) + (q_ << 13) + (tid << 4)); \
    } } while (0)

#define PHASE(buf, mh, nh, LOADA, LOADB, STAGE_STMT, VM_STMT) do { \
    if (LOADA) { \
      _Pragma("unroll") for (int mi = 0; mi < 4; ++mi) \
      _Pragma("unroll") for (int kk = 0; kk < 2; ++kk) \
        fa[mi][kk] = *(const short8*)(lds + ((buf) << 16) + ((mh) << 14) + aRowByte[mi] + colByte[kk]); \
    } \
    if (LOADB) { \
      _Pragma("unroll") for (int ni = 0; ni < 2; ++ni) \
      _Pragma("unroll") for (int kk = 0; kk < 2; ++kk) \
        fb[ni][kk] = *(const short8*)(lds + ((buf) << 16) + 32768 + ((nh) << 14) + bRowByte[ni] + colByte[kk]); \
    } \
    STAGE_STMT; \
    VM_STMT; \
    __builtin_amdgcn_s_barrier(); \
    SCHED_RELAX; \
    __builtin_amdgcn_s_setprio(1); \
    _Pragma("unroll") for (int mi = 0; mi < 4; ++mi) \
    _Pragma("unroll") for (int ni = 0; ni < 2; ++ni) \
    _Pragma("unroll") for (int kk = 0; kk < 2; ++kk) \
      acc[(mh) * 4 + mi][(nh) * 2 + ni] = __builtin_amdgcn_mfma_f32_16x16x32_bf16( \
          fa[mi][kk], fb[ni][kk], acc[(mh) * 4 + mi][(nh) * 2 + ni], 0, 0, 0); \
    __builtin_amdgcn_s_setprio(0); \
    __builtin_amdgcn_s_barrier(); \
    SCHED_RELAX; \
  } while (0)

__global__ void __launch_bounds__(512, 2)
k_gemm(const unsigned short* __restrict__ xp,
       const unsigned short* __restrict__ Wp,
       const float* __restrict__ bias,
       float* __restrict__ out) {
  __shared__ __attribute__((aligned(16))) unsigned char lds[131072];

  const int tid  = threadIdx.x;
  const int lane = tid & 63;
  const int w    = tid >> 6;       // 0..7
  const int wm   = w >> 2;         // 0..1
  const int wn   = w & 3;          // 0..3

  // bijective XCD swizzle (256 blocks, 256 % 8 == 0): each XCD gets a
  // contiguous 8-mtile x 4-ntile chunk -> A fetched once per XCD.
  const int bid = blockIdx.x;
  const int swz = (bid & 7) * 32 + (bid >> 3);
  const int m0 = (swz >> 2) * BM;
  const int n0 = (swz & 3) * BN;
  const int b  = m0 >> 11;
  const int l0 = m0 & 2047;

  // ---- staging geometry (per thread) ----
  const int sr0 = tid >> 3;                                  // region row, issue q adds q*64
  const int clog = ((tid & 7) ^ (sr0 & 7)) << 3;             // pre-swizzled source elem offset
  const int aRowBase = b * LPAD + l0 + 3 + sr0;
  const int nBase0 = n0 + ((sr0 >> 5) << 6) + (sr0 & 31);

  // ---- ds_read geometry (per thread) ----
  int aRowByte[4], bRowByte[2], colByte[2];
#pragma unroll
  for (int mi = 0; mi < 4; ++mi) aRowByte[mi] = (wm * 64 + mi * 16 + (lane & 15)) << 7;
#pragma unroll
  for (int ni = 0; ni < 2; ++ni) bRowByte[ni] = (wn * 32 + ni * 16 + (lane & 15)) << 7;
#pragma unroll
  for (int kk = 0; kk < 2; ++kk)
    colByte[kk] = (kk * 64 + ((lane >> 4) << 4)) ^ ((lane & 7) << 4);

  f32x4 acc[8][4] = {};
  short8 fa[4][2], fb[2][2];

  // ---- prologue: tile0 (buf0) fully, tile1 (buf1) 3 halves ----
  STAGE_A(0, 0, 0);
  STAGE_B(0, 0, 1);
  STAGE_A(0, 0, 1);
  STAGE_B(0, 0, 0);
  VM4;
  STAGE_A(1, 1, 0);
  STAGE_B(1, 1, 1);
  STAGE_A(1, 1, 1);
  VM6;                               // tile0 fully landed (per-wave)
  __builtin_amdgcn_s_barrier();      // all waves' tile0 landed
  SCHED_RELAX;

  // ---- main loop: 31 iters, tiles 0..61 ----
#pragma unroll 1
  for (int it = 0; it < 31; ++it) {
    const int kt0 = it * 2;
    PHASE(0, 0, 0, 1, 1, STAGE_B(1, kt0 + 1, 0), NOPS);
    PHASE(0, 0, 1, 0, 1, STAGE_A(0, kt0 + 2, 0), NOPS);
    PHASE(0, 1, 1, 1, 0, STAGE_B(0, kt0 + 2, 1), NOPS);
    PHASE(0, 1, 0, 0, 1, STAGE_A(0, kt0 + 2, 1), VM6);   // tile kt0+1 landed
    PHASE(1, 0, 0, 1, 1, STAGE_B(0, kt0 + 2, 0), NOPS);
    PHASE(1, 0, 1, 0, 1, STAGE_A(1, kt0 + 3, 0), NOPS);
    PHASE(1, 1, 1, 1, 0, STAGE_B(1, kt0 + 3, 1), NOPS);
    PHASE(1, 1, 0, 0, 1, STAGE_A(1, kt0 + 3, 1), VM6);   // tile kt0+2 landed
  }

  // ---- epilogue: tiles 62 (buf0), 63 (buf1) ----
  PHASE(0, 0, 0, 1, 1, STAGE_B(1, 63, 0), NOPS);
  PHASE(0, 0, 1, 0, 1, NOPS, NOPS);
  PHASE(0, 1, 1, 1, 0, NOPS, NOPS);
  PHASE(0, 1, 0, 0, 1, NOPS, VM0);                        // tile 63 landed
  PHASE(1, 0, 0, 1, 1, NOPS, NOPS);
  PHASE(1, 0, 1, 0, 1, NOPS, NOPS);
  PHASE(1, 1, 1, 1, 0, NOPS, NOPS);
  PHASE(1, 1, 0, 0, 1, NOPS, NOPS);

  // ---- C write: col = lane&15, row = (lane>>4)*4 + reg ----
#pragma unroll
  for (int nig = 0; nig < 4; ++nig) {
    const int col = n0 + wn * 64 + nig * 16 + (lane & 15);
    const float bv = bias[col];
#pragma unroll
    for (int mig = 0; mig < 8; ++mig) {
      const int row0 = m0 + wm * 128 + mig * 16 + ((lane >> 4) << 2);
#pragma unroll
      for (int t2 = 0; t2 < 4; ++t2)
        out[(size_t)(row0 + t2) * Dq + col] = acc[mig][nig][t2] + bv;
    }
  }
}

// ---- slow-but-correct fallback if workspace is too small ----
__global__ void k_naive(const float* __restrict__ x, const float* __restrict__ W,
                        const float* __restrict__ bias, float* __restrict__ out) {
  size_t g = (size_t)blockIdx.x * blockDim.x + threadIdx.x;
  const size_t total = (size_t)Bq * Lq * Dq;
  if (g >= total) return;
  int d = (int)(g & 1023);
  int l = (int)((g >> 10) & 2047);
  int b = (int)(g >> 21);
  float s = bias[d];
  for (int i = 0; i < Pq; ++i) {
    if (l - i < 0) continue;
    const float* xr = x + ((size_t)b * Lq + (l - i)) * Dq;
    const float* wr = W + (size_t)d * Kq + i;
    float accv = 0.f;
    for (int dp = 0; dp < Dq; ++dp) accv += xr[dp] * wr[(size_t)dp * 4];
    s += accv;
  }
  out[g] = s;
}

extern "C" void kernel_launch(void* const* d_in, const int* in_sizes, int n_in,
                              void* d_out, int out_size, void* d_ws, size_t ws_size,
                              hipStream_t stream) {
  const float* x    = (const float*)d_in[0];
  const float* W    = (const float*)d_in[1];
  const float* bias = (const float*)d_in[2];
  float* out = (float*)d_out;

  const size_t WP_BYTES = (size_t)Dq * Kq * sizeof(unsigned short);        // 8 MiB
  const size_t XP_BYTES = (size_t)Bq * LPAD * Dq * sizeof(unsigned short); // ~33.7 MB

  if (ws_size < WP_BYTES + XP_BYTES) {
    const size_t total = (size_t)Bq * Lq * Dq;
    k_naive<<<(unsigned)((total + 255) / 256), 256, 0, stream>>>(x, W, bias, out);
    return;
  }

  unsigned short* Wp = (unsigned short*)d_ws;
  unsigned short* xp = (unsigned short*)((char*)d_ws + WP_BYTES);

  k_prep<<<10272, 256, 0, stream>>>(x, W, xp, Wp);
  k_gemm<<<dim3((Bq * Lq / BM) * (Dq / BN)), 512, 0, stream>>>(xp, Wp, bias, out);
}